// Round 4
// baseline (164.547 us; speedup 1.0000x reference)
//
#include <hip/hip_runtime.h>
#include <hip/hip_bf16.h>

// MHA forward: b=2, s=2048, d=1024, h=16, dk=64. fp32 in/out, bf16 MFMA internally.
// ws layout (40.5 MB):
//   0      : xb [4096][1024] bf16 (8MB)   -- dead after gemm_qkv, reused as VbT[32][64][2048]
//   8 MB   : Wqkvb [3072][1024] bf16 (6MB)  rows 0-1023=Wq*log2e/8, 1024-2047=Wk, 2048-3071=Wv
//   14 MB  : Wob [1024][1024] bf16 (2MB)
//   16 MB  : Qb [4096][1024] bf16 (8MB)  (RoPE'd, log2-domain scale)
//   24 MB  : Kb [4096][1024] bf16 (8MB)  (RoPE'd)
//   32 MB  : Vb [4096][1024] bf16 (8MB)  -- dead after transpose_v, reused as Ob
//   40 MB  : cosT [2048][32] f32, sinT [2048][32] f32

typedef __attribute__((ext_vector_type(8))) __bf16 bf16x8;
typedef __attribute__((ext_vector_type(4))) float f32x4;
typedef __attribute__((ext_vector_type(16))) float f32x16;
typedef __attribute__((ext_vector_type(4))) int int4v;
typedef __attribute__((ext_vector_type(2))) unsigned int uint2v;

#define MFMA16(a, b, c) __builtin_amdgcn_mfma_f32_16x16x32_bf16(a, b, c, 0, 0, 0)
#define MFMA32(a, b, c) __builtin_amdgcn_mfma_f32_32x32x16_bf16(a, b, c, 0, 0, 0)

__device__ inline unsigned short f2b(float f) {
  unsigned u = __builtin_bit_cast(unsigned, f);
  u = (u + 0x7FFF + ((u >> 16) & 1)) >> 16;   // RNE, finite inputs only
  return (unsigned short)u;
}

__device__ inline unsigned cvtpk(float lo, float hi) {
  unsigned r;
  asm("v_cvt_pk_bf16_f32 %0, %1, %2" : "=v"(r) : "v"(lo), "v"(hi));
  return r;
}

__device__ inline void plswap(unsigned a, unsigned b, unsigned& o0, unsigned& o1) {
#if __has_builtin(__builtin_amdgcn_permlane32_swap)
  auto r = __builtin_amdgcn_permlane32_swap(a, b, false, false);
  o0 = r[0];
  o1 = r[1];
#else
  unsigned sa = (unsigned)__shfl_xor((int)a, 32, 64);
  unsigned sb = (unsigned)__shfl_xor((int)b, 32, 64);
  bool hi = (threadIdx.x & 32) != 0;
  o0 = hi ? sb : a;
  o1 = hi ? b : sa;
#endif
}

__device__ inline float fexp2(float x) {
#if __has_builtin(__builtin_amdgcn_exp2f)
  return __builtin_amdgcn_exp2f(x);
#else
  return exp2f(x);
#endif
}

// ---------------- fused prep ----------------

__device__ inline void cvt4(const float* __restrict__ s, unsigned short* __restrict__ d,
                            int i, float sc) {
  float4 v = *(const float4*)(s + i);
  unsigned p0 = (unsigned)f2b(v.x * sc) | ((unsigned)f2b(v.y * sc) << 16);
  unsigned p1 = (unsigned)f2b(v.z * sc) | ((unsigned)f2b(v.w * sc) << 16);
  uint2v p = {p0, p1};
  *(uint2v*)(d + i) = p;
}

__global__ __launch_bounds__(256) void prep_kernel(
    const float* __restrict__ x, const float* __restrict__ Wq,
    const float* __restrict__ Wk, const float* __restrict__ Wv,
    const float* __restrict__ Wo, const int* __restrict__ tp,
    unsigned short* __restrict__ xb, unsigned short* __restrict__ Wqkvb,
    unsigned short* __restrict__ Wob, float* __restrict__ cosT,
    float* __restrict__ sinT) {
  int t = blockIdx.x * 256 + threadIdx.x;
  if (t < 1048576) {
    cvt4(x, xb, t * 4, 1.0f);
  } else if (t < 1310720) {
    cvt4(Wq, Wqkvb, (t - 1048576) * 4, 0.18033688f);   // (1/8)*log2(e)
  } else if (t < 1572864) {
    cvt4(Wk, Wqkvb + 1048576, (t - 1310720) * 4, 1.0f);
  } else if (t < 1835008) {
    cvt4(Wv, Wqkvb + 2097152, (t - 1572864) * 4, 1.0f);
  } else if (t < 2097152) {
    cvt4(Wo, Wob, (t - 1835008) * 4, 1.0f);
  } else {
    int base = (t - 2097152) * 4;
#pragma unroll
    for (int j = 0; j < 4; ++j) {
      int idx = base + j;
      int p = idx >> 5, i = idx & 31;
      float pos = (float)tp[p];
      float freq = powf(10000.0f, -(float)i / 32.0f);
      float ang = pos * freq;
      cosT[idx] = cosf(ang);
      sinT[idx] = sinf(ang);
    }
  }
}

// ---------------- GEMM 1: QKV projection + RoPE epilogue (BK=64) ----------------

__global__ __launch_bounds__(256) void gemm_qkv_kernel(
    const unsigned short* __restrict__ A,    // xb
    const unsigned short* __restrict__ B,    // Wqkvb
    unsigned short* __restrict__ Qb, unsigned short* __restrict__ Kb,
    unsigned short* __restrict__ Vb,
    const float* __restrict__ cosT, const float* __restrict__ sinT) {
  __shared__ unsigned short As[128 * 64];
  __shared__ unsigned short Bs[128 * 64];
  const int m0 = blockIdx.y * 128, n0 = blockIdx.x * 128;
  const int tid = threadIdx.x, w = tid >> 6, lane = tid & 63;
  const int l15 = lane & 15, l4 = lane >> 4;
  const int wr = w >> 1, wc = w & 1;
  const int srow = lane >> 3, scol = (lane & 7) * 8;

  f32x4 acc[4][4] = {};

  for (int k0 = 0; k0 < 1024; k0 += 64) {
    __syncthreads();
#pragma unroll
    for (int c = 0; c < 4; ++c) {
      const int rb = w * 32 + c * 8;
      const unsigned short* ga = A + (size_t)(m0 + rb + srow) * 1024 + k0 + scol;
      __builtin_amdgcn_global_load_lds(
          (const __attribute__((address_space(1))) void*)ga,
          (__attribute__((address_space(3))) void*)(&As[rb * 64]), 16, 0, 0);
      const unsigned short* gb = B + (size_t)(n0 + rb + srow) * 1024 + k0 + scol;
      __builtin_amdgcn_global_load_lds(
          (const __attribute__((address_space(1))) void*)gb,
          (__attribute__((address_space(3))) void*)(&Bs[rb * 64]), 16, 0, 0);
    }
    __syncthreads();
#pragma unroll
    for (int kk = 0; kk < 2; ++kk) {
      bf16x8 af[4], bfr[4];
#pragma unroll
      for (int m = 0; m < 4; m++)
        af[m] = *(const bf16x8*)(&As[(wr * 64 + m * 16 + l15) * 64 + kk * 32 + l4 * 8]);
#pragma unroll
      for (int n = 0; n < 4; n++)
        bfr[n] = *(const bf16x8*)(&Bs[(wc * 64 + n * 16 + l15) * 64 + kk * 32 + l4 * 8]);
#pragma unroll
      for (int m = 0; m < 4; m++)
#pragma unroll
        for (int n = 0; n < 4; n++)
          acc[m][n] = MFMA16(af[m], bfr[n], acc[m][n]);
    }
  }

  const bool rope = (n0 < 2048);
  unsigned short* dst = (n0 < 1024) ? Qb : (n0 < 2048 ? Kb : Vb);
  const int cbase = (n0 & 1023);
#pragma unroll
  for (int m = 0; m < 4; m++) {
#pragma unroll
    for (int n = 0; n < 4; n++) {
#pragma unroll
      for (int r = 0; r < 4; r++) {
        int row = m0 + wr * 64 + m * 16 + l4 * 4 + r;
        int col = cbase + wc * 64 + n * 16 + l15;
        float v = acc[m][n][r];
        float pv = __shfl_xor(v, 1, 64);      // value of col^1 (lives in lane^1)
        unsigned pk;
        if (rope) {
          float x1 = (l15 & 1) ? pv : v;
          float x2 = (l15 & 1) ? v : pv;
          int pos = row & 2047;
          int pi = (col & 63) >> 1;
          float c = cosT[pos * 32 + pi], s = sinT[pos * 32 + pi];
          float r1 = fmaf(x1, c, -x2 * s);
          float r2 = fmaf(x2, c, x1 * s);
          pk = (unsigned)f2b(r1) | ((unsigned)f2b(r2) << 16);
        } else {
          pk = (unsigned)f2b(v) | ((unsigned)f2b(pv) << 16);
        }
        if (!(l15 & 1))
          *(unsigned*)(dst + (size_t)row * 1024 + col) = pk;
      }
    }
  }
}

// ---------------- GEMM 2: output projection (BK=64) ----------------

__global__ __launch_bounds__(256) void gemm_out_kernel(
    const unsigned short* __restrict__ A,    // Ob [4096][1024]
    const unsigned short* __restrict__ B,    // Wob [1024][1024]
    float* __restrict__ out) {
  __shared__ unsigned short As[128 * 64];
  __shared__ unsigned short Bs[128 * 64];
  const int m0 = blockIdx.y * 128, n0 = blockIdx.x * 128;
  const int tid = threadIdx.x, w = tid >> 6, lane = tid & 63;
  const int l15 = lane & 15, l4 = lane >> 4;
  const int wr = w >> 1, wc = w & 1;
  const int srow = lane >> 3, scol = (lane & 7) * 8;

  f32x4 acc[4][4] = {};

  for (int k0 = 0; k0 < 1024; k0 += 64) {
    __syncthreads();
#pragma unroll
    for (int c = 0; c < 4; ++c) {
      const int rb = w * 32 + c * 8;
      const unsigned short* ga = A + (size_t)(m0 + rb + srow) * 1024 + k0 + scol;
      __builtin_amdgcn_global_load_lds(
          (const __attribute__((address_space(1))) void*)ga,
          (__attribute__((address_space(3))) void*)(&As[rb * 64]), 16, 0, 0);
      const unsigned short* gb = B + (size_t)(n0 + rb + srow) * 1024 + k0 + scol;
      __builtin_amdgcn_global_load_lds(
          (const __attribute__((address_space(1))) void*)gb,
          (__attribute__((address_space(3))) void*)(&Bs[rb * 64]), 16, 0, 0);
    }
    __syncthreads();
#pragma unroll
    for (int kk = 0; kk < 2; ++kk) {
      bf16x8 af[4], bfr[4];
#pragma unroll
      for (int m = 0; m < 4; m++)
        af[m] = *(const bf16x8*)(&As[(wr * 64 + m * 16 + l15) * 64 + kk * 32 + l4 * 8]);
#pragma unroll
      for (int n = 0; n < 4; n++)
        bfr[n] = *(const bf16x8*)(&Bs[(wc * 64 + n * 16 + l15) * 64 + kk * 32 + l4 * 8]);
#pragma unroll
      for (int m = 0; m < 4; m++)
#pragma unroll
        for (int n = 0; n < 4; n++)
          acc[m][n] = MFMA16(af[m], bfr[n], acc[m][n]);
    }
  }

#pragma unroll
  for (int m = 0; m < 4; m++)
#pragma unroll
    for (int n = 0; n < 4; n++)
#pragma unroll
      for (int r = 0; r < 4; r++) {
        int row = m0 + wr * 64 + m * 16 + l4 * 4 + r;
        int col = n0 + wc * 64 + n * 16 + l15;
        out[(size_t)row * 1024 + col] = acc[m][n][r];
      }
}

// ---------------- V transpose: Vb[4096][1024] -> VbT[32 bh][64 dk][2048 seq] ----------------

__global__ __launch_bounds__(256) void transpose_v(
    const unsigned short* __restrict__ Vb, unsigned short* __restrict__ VbT) {
  __shared__ unsigned short T[128][72];
  const int bh = blockIdx.x, st = blockIdx.y;   // 32 x 16 (128 seq per tile)
  const int b = bh >> 4, h = bh & 15;
  const int tid = threadIdx.x;
  {
    const int r = tid >> 1, c = (tid & 1) * 32;
    const unsigned short* g = Vb + (size_t)(b * 2048 + st * 128 + r) * 1024 + h * 64 + c;
#pragma unroll
    for (int j = 0; j < 4; ++j)
      *(int4v*)(&T[r][c + j * 8]) = *(const int4v*)(g + j * 8);
  }
  __syncthreads();
  {
    const int dk = tid & 63, sc = (tid >> 6) * 32;
    unsigned pk[16];
#pragma unroll
    for (int j = 0; j < 16; ++j)
      pk[j] = (unsigned)T[sc + 2 * j][dk] | ((unsigned)T[sc + 2 * j + 1][dk] << 16);
    unsigned short* g = VbT + (size_t)bh * 131072 + (size_t)dk * 2048 + st * 128 + sc;
#pragma unroll
    for (int j = 0; j < 4; ++j) {
      int4v ov;
      ov[0] = (int)pk[j * 4 + 0]; ov[1] = (int)pk[j * 4 + 1];
      ov[2] = (int)pk[j * 4 + 2]; ov[3] = (int)pk[j * 4 + 3];
      *(int4v*)(g + j * 8) = ov;
    }
  }
}

// ---------------- Flash attention: paired q-chunks, 3-buf counted-vmcnt pipeline --------

__device__ __forceinline__ void stage_tiles(const unsigned short* __restrict__ Kgb,
                                            const unsigned short* __restrict__ Vgb,
                                            unsigned short* KsBuf, unsigned short* VsBuf,
                                            int kv0, int w, int lane) {
#pragma unroll
  for (int c = 0; c < 2; ++c) {
    const int rowbase = w * 16 + c * 8;
    const int row = rowbase + (lane >> 3);
    const int chunk = (lane & 7) ^ (lane >> 3);    // inverse swizzle on global source
    const unsigned short* gk = Kgb + (size_t)(kv0 + row) * 1024 + chunk * 8;
    __builtin_amdgcn_global_load_lds(
        (const __attribute__((address_space(1))) void*)gk,
        (__attribute__((address_space(3))) void*)(KsBuf + rowbase * 64), 16, 0, 0);
    const unsigned short* gv = Vgb + (size_t)row * 2048 + kv0 + chunk * 8;
    __builtin_amdgcn_global_load_lds(
        (const __attribute__((address_space(1))) void*)gv,
        (__attribute__((address_space(3))) void*)(VsBuf + rowbase * 64), 16, 0, 0);
  }
}

__device__ __forceinline__ void attn_chunk(
    int qt, int b, int h, int w, int lane,
    const unsigned short* __restrict__ Qb,
    const unsigned short* __restrict__ Kgb,
    const unsigned short* __restrict__ Vgb,
    unsigned short* __restrict__ Ob,
    unsigned short (*Ks)[64 * 64], unsigned short (*Vs)[64 * 64]) {
  const int l31 = lane & 31, l32 = lane >> 5;
  const int sw = l31 & 7;

  const unsigned short* qptr =
      Qb + (size_t)(b * 2048 + qt * 128 + w * 32 + l31) * 1024 + h * 64 + l32 * 8;
  bf16x8 qa[4];
#pragma unroll
  for (int kk = 0; kk < 4; ++kk) qa[kk] = *(const bf16x8*)(qptr + kk * 16);

  f32x16 oacc[2] = {};
  float m = -3e38f, l = 0.f;

  const int nt = 2 * qt + 2;
  // prologue: 2 tiles in flight
  stage_tiles(Kgb, Vgb, Ks[0], Vs[0], 0, w, lane);
  if (nt > 1) stage_tiles(Kgb, Vgb, Ks[1], Vs[1], 64, w, lane);

  int ib = 0, is_ = 2;
  for (int t = 0; t < nt; ++t) {
    if (t < nt - 1) {
      asm volatile("s_waitcnt vmcnt(4)" ::: "memory");
    } else {
      asm volatile("s_waitcnt vmcnt(0)" ::: "memory");
    }
    __builtin_amdgcn_s_barrier();
    __builtin_amdgcn_sched_barrier(0);
    if (t + 2 < nt)
      stage_tiles(Kgb, Vgb, Ks[is_], Vs[is_], (t + 2) * 64, w, lane);

    // QK^T swapped: St = mfma32(K_frag, Q_frag) -> S^T[kv][q], q = l31
    const char* ksb = (const char*)Ks[ib];
    f32x16 st[2];
#pragma unroll
    for (int f = 0; f < 2; ++f) {
      const char* kb = ksb + (f * 32 + l31) * 128;
      f32x16 z = {};
#pragma unroll
      for (int kk = 0; kk < 4; ++kk) {
        bf16x8 kf = *(const bf16x8*)(kb + ((((kk << 1) | l32) ^ sw) * 16));
        z = MFMA32(kf, qa[kk], z);
      }
      st[f] = z;
    }

    // causal mask (diagonal tiles only)
    if (t >= 2 * qt + (w >> 1)) {
      const int qg = qt * 128 + w * 32 + l31;
      const int kvb = t * 64 + 4 * l32;
#pragma unroll
      for (int f = 0; f < 2; ++f)
#pragma unroll
        for (int reg = 0; reg < 16; ++reg) {
          int kv = kvb + 32 * f + (reg & 3) + 8 * (reg >> 2);
          if (kv > qg) st[f][reg] = -3e38f;
        }
    }

    // row max: in-register tree + 1 swap across lane halves
    float a8[8];
#pragma unroll
    for (int j = 0; j < 8; ++j)
      a8[j] = fmaxf(fmaxf(st[0][j], st[0][j + 8]), fmaxf(st[1][j], st[1][j + 8]));
    float pm = fmaxf(fmaxf(fmaxf(a8[0], a8[1]), fmaxf(a8[2], a8[3])),
                     fmaxf(fmaxf(a8[4], a8[5]), fmaxf(a8[6], a8[7])));
    pm = fmaxf(pm, __shfl_xor(pm, 32, 64));

    // defer-max: rescale only when running max grew by > 8 (log2 domain)
    if (!__all(pm - m <= 8.0f)) {
      float mn = fmaxf(m, pm);
      float al = fexp2(m - mn);
      l *= al;
#pragma unroll
      for (int df = 0; df < 2; ++df)
#pragma unroll
        for (int reg = 0; reg < 16; ++reg) oacc[df][reg] *= al;
      m = mn;
    }

    // p = exp2(s - m), pack to bf16 pairs
    unsigned pku[2][4][2];
    float rs0 = 0.f, rs1 = 0.f;
#pragma unroll
    for (int f = 0; f < 2; ++f)
#pragma unroll
      for (int rr = 0; rr < 4; ++rr)
#pragma unroll
        for (int i = 0; i < 2; ++i) {
          float p0 = fexp2(st[f][4 * rr + 2 * i] - m);
          float p1 = fexp2(st[f][4 * rr + 2 * i + 1] - m);
          rs0 += p0; rs1 += p1;
          pku[f][rr][i] = cvtpk(p0, p1);
        }
    float rs = rs0 + rs1;
    rs += __shfl_xor(rs, 32, 64);
    l += rs;

    // redistribute P^T into B-operand frags via permlane32_swap
    union FB { unsigned u[4]; bf16x8 v; };
    FB pfrag[4];
#pragma unroll
    for (int kk = 0; kk < 4; ++kk) {
      const int f = kk >> 1, kl = kk & 1;
      unsigned o00, o10, o01, o11;
      plswap(pku[f][2 * kl][0], pku[f][2 * kl + 1][0], o00, o10);
      plswap(pku[f][2 * kl][1], pku[f][2 * kl + 1][1], o01, o11);
      pfrag[kk].u[0] = o00; pfrag[kk].u[1] = o01;
      pfrag[kk].u[2] = o10; pfrag[kk].u[3] = o11;
    }

    // PV swapped: O^T[d][q] += mfma32(V^T_frag, P^T_frag)
    const char* vsb = (const char*)Vs[ib];
#pragma unroll
    for (int df = 0; df < 2; ++df) {
      const char* vb = vsb + (df * 32 + l31) * 128;
#pragma unroll
      for (int kk = 0; kk < 4; ++kk) {
        bf16x8 vf = *(const bf16x8*)(vb + ((((kk << 1) | l32) ^ sw) * 16));
        oacc[df] = MFMA32(vf, pfrag[kk].v, oacc[df]);
      }
    }

    ib = (ib == 2) ? 0 : ib + 1;
    is_ = (is_ == 2) ? 0 : is_ + 1;
  }

  // epilogue: O[q][d], d = df*32 + 8*rr + 4*l32 + 2i (+1)
  const float inv = 1.0f / l;
  unsigned short* ob =
      Ob + (size_t)(b * 2048 + qt * 128 + w * 32 + l31) * 1024 + h * 64 + 4 * l32;
#pragma unroll
  for (int df = 0; df < 2; ++df)
#pragma unroll
    for (int rr = 0; rr < 4; ++rr)
#pragma unroll
      for (int i = 0; i < 2; ++i) {
        unsigned pk2 = (unsigned)f2b(oacc[df][4 * rr + 2 * i] * inv) |
                       ((unsigned)f2b(oacc[df][4 * rr + 2 * i + 1] * inv) << 16);
        *(unsigned*)(ob + df * 32 + rr * 8 + 2 * i) = pk2;
      }
}

__global__ __launch_bounds__(256) void attn_kernel(
    const unsigned short* __restrict__ Qb,
    const unsigned short* __restrict__ Kb,
    const unsigned short* __restrict__ VbT,   // [32][64][2048]
    unsigned short* __restrict__ Ob) {
  __shared__ unsigned short Ks[3][64 * 64];   // 3-deep pipeline, chunk-swizzled
  __shared__ unsigned short Vs[3][64 * 64];
  const int bh = blockIdx.x;                  // fastest -> same bh lands on one XCD
  const int pair = blockIdx.y;                // 0..7
  const int b = bh >> 4, h = bh & 15;
  const int tid = threadIdx.x, w = tid >> 6, lane = tid & 63;

  const unsigned short* Kgb = Kb + (size_t)b * 2048 * 1024 + h * 64;
  const unsigned short* Vgb = VbT + (size_t)bh * 131072;

  attn_chunk(pair, b, h, w, lane, Qb, Kgb, Vgb, Ob, Ks, Vs);
  __syncthreads();   // all waves done reading chunk-A tiles before re-staging
  attn_chunk(15 - pair, b, h, w, lane, Qb, Kgb, Vgb, Ob, Ks, Vs);
}

// ---------------- launch ----------------

extern "C" void kernel_launch(void* const* d_in, const int* in_sizes, int n_in,
                              void* d_out, int out_size, void* d_ws, size_t ws_size,
                              hipStream_t stream) {
  (void)in_sizes; (void)n_in; (void)out_size; (void)ws_size;
  const float* x  = (const float*)d_in[0];
  const int*  tp  = (const int*)d_in[1];
  const float* Wq = (const float*)d_in[2];
  const float* Wk = (const float*)d_in[3];
  const float* Wv = (const float*)d_in[4];
  const float* Wo = (const float*)d_in[5];
  float* out = (float*)d_out;

  char* ws = (char*)d_ws;
  unsigned short* xb    = (unsigned short*)(ws);                       // 8MB
  unsigned short* VbT   = (unsigned short*)(ws);                       // reuses xb
  unsigned short* Wqkvb = (unsigned short*)(ws + (8ull << 20));        // 6MB
  unsigned short* Wob   = (unsigned short*)(ws + (14ull << 20));       // 2MB
  unsigned short* Qb    = (unsigned short*)(ws + (16ull << 20));       // 8MB
  unsigned short* Kb    = (unsigned short*)(ws + (24ull << 20));       // 8MB
  unsigned short* Vb    = (unsigned short*)(ws + (32ull << 20));       // 8MB
  unsigned short* Ob    = (unsigned short*)(ws + (32ull << 20));       // reuses Vb
  float* cosT = (float*)(ws + (40ull << 20));
  float* sinT = (float*)(ws + (40ull << 20) + 2048 * 32 * 4);

  prep_kernel<<<8256, 256, 0, stream>>>(x, Wq, Wk, Wv, Wo, tp, xb, Wqkvb, Wob, cosT, sinT);
  gemm_qkv_kernel<<<dim3(24, 32), 256, 0, stream>>>(xb, Wqkvb, Qb, Kb, Vb, cosT, sinT);
  transpose_v<<<dim3(32, 16), 256, 0, stream>>>(Vb, VbT);
  attn_kernel<<<dim3(32, 8), 256, 0, stream>>>(Qb, Kb, VbT, Ob);
  gemm_out_kernel<<<dim3(8, 32), 256, 0, stream>>>(Ob, Wob, out);
}

// Round 5
// 157.041 us; speedup vs baseline: 1.0478x; 1.0478x over previous
//
#include <hip/hip_runtime.h>
#include <hip/hip_bf16.h>

// MHA forward: b=2, s=2048, d=1024, h=16, dk=64. fp32 in/out, bf16 MFMA internally.
// ws layout (40.5 MB):
//   0      : xb [4096][1024] bf16 (8MB)   -- dead after gemm_qkv, reused as VbT[32][64][2048]
//   8 MB   : Wqkvb [3072][1024] bf16 (6MB)  rows 0-1023=Wq*log2e/8, 1024-2047=Wk, 2048-3071=Wv
//   14 MB  : Wob [1024][1024] bf16 (2MB)
//   16 MB  : Qb [4096][1024] bf16 (8MB)  (RoPE'd, log2-domain scale)
//   24 MB  : Kb [4096][1024] bf16 (8MB)  (RoPE'd)
//   32 MB  : Vb [4096][1024] bf16 (8MB)  -- dead after transpose_v, reused as Ob
//   40 MB  : cosT [2048][32] f32, sinT [2048][32] f32

typedef __attribute__((ext_vector_type(8))) __bf16 bf16x8;
typedef __attribute__((ext_vector_type(4))) float f32x4;
typedef __attribute__((ext_vector_type(16))) float f32x16;
typedef __attribute__((ext_vector_type(4))) int int4v;
typedef __attribute__((ext_vector_type(2))) unsigned int uint2v;

#define MFMA16(a, b, c) __builtin_amdgcn_mfma_f32_16x16x32_bf16(a, b, c, 0, 0, 0)
#define MFMA32(a, b, c) __builtin_amdgcn_mfma_f32_32x32x16_bf16(a, b, c, 0, 0, 0)

__device__ inline unsigned short f2b(float f) {
  unsigned u = __builtin_bit_cast(unsigned, f);
  u = (u + 0x7FFF + ((u >> 16) & 1)) >> 16;   // RNE, finite inputs only
  return (unsigned short)u;
}

__device__ inline unsigned cvtpk(float lo, float hi) {
  unsigned r;
  asm("v_cvt_pk_bf16_f32 %0, %1, %2" : "=v"(r) : "v"(lo), "v"(hi));
  return r;
}

__device__ inline void plswap(unsigned a, unsigned b, unsigned& o0, unsigned& o1) {
#if __has_builtin(__builtin_amdgcn_permlane32_swap)
  auto r = __builtin_amdgcn_permlane32_swap(a, b, false, false);
  o0 = r[0];
  o1 = r[1];
#else
  unsigned sa = (unsigned)__shfl_xor((int)a, 32, 64);
  unsigned sb = (unsigned)__shfl_xor((int)b, 32, 64);
  bool hi = (threadIdx.x & 32) != 0;
  o0 = hi ? sb : a;
  o1 = hi ? b : sa;
#endif
}

__device__ inline float fexp2(float x) {
#if __has_builtin(__builtin_amdgcn_exp2f)
  return __builtin_amdgcn_exp2f(x);
#else
  return exp2f(x);
#endif
}

// ---------------- fused prep ----------------

__device__ inline void cvt4(const float* __restrict__ s, unsigned short* __restrict__ d,
                            int i, float sc) {
  float4 v = *(const float4*)(s + i);
  unsigned p0 = (unsigned)f2b(v.x * sc) | ((unsigned)f2b(v.y * sc) << 16);
  unsigned p1 = (unsigned)f2b(v.z * sc) | ((unsigned)f2b(v.w * sc) << 16);
  uint2v p = {p0, p1};
  *(uint2v*)(d + i) = p;
}

__global__ __launch_bounds__(256) void prep_kernel(
    const float* __restrict__ x, const float* __restrict__ Wq,
    const float* __restrict__ Wk, const float* __restrict__ Wv,
    const float* __restrict__ Wo, const int* __restrict__ tp,
    unsigned short* __restrict__ xb, unsigned short* __restrict__ Wqkvb,
    unsigned short* __restrict__ Wob, float* __restrict__ cosT,
    float* __restrict__ sinT) {
  int t = blockIdx.x * 256 + threadIdx.x;
  if (t < 1048576) {
    cvt4(x, xb, t * 4, 1.0f);
  } else if (t < 1310720) {
    cvt4(Wq, Wqkvb, (t - 1048576) * 4, 0.18033688f);   // (1/8)*log2(e)
  } else if (t < 1572864) {
    cvt4(Wk, Wqkvb + 1048576, (t - 1310720) * 4, 1.0f);
  } else if (t < 1835008) {
    cvt4(Wv, Wqkvb + 2097152, (t - 1572864) * 4, 1.0f);
  } else if (t < 2097152) {
    cvt4(Wo, Wob, (t - 1835008) * 4, 1.0f);
  } else {
    int base = (t - 2097152) * 4;
#pragma unroll
    for (int j = 0; j < 4; ++j) {
      int idx = base + j;
      int p = idx >> 5, i = idx & 31;
      float pos = (float)tp[p];
      float freq = powf(10000.0f, -(float)i / 32.0f);
      float ang = pos * freq;
      cosT[idx] = cosf(ang);
      sinT[idx] = sinf(ang);
    }
  }
}

// ---------------- GEMM 1: QKV projection + RoPE epilogue (BK=64, XOR-swizzled LDS) ------
// swizzle (rule #21, both sides): LDS dest linear; global source chunk = (lane&7)^(lane>>3);
// fragment read chunk = (kk*4+l4)^(row&7)  ->  bank spread 8 groups, 2-way (free).

__global__ __launch_bounds__(256) void gemm_qkv_kernel(
    const unsigned short* __restrict__ A,    // xb
    const unsigned short* __restrict__ B,    // Wqkvb
    unsigned short* __restrict__ Qb, unsigned short* __restrict__ Kb,
    unsigned short* __restrict__ Vb,
    const float* __restrict__ cosT, const float* __restrict__ sinT) {
  __shared__ unsigned short As[128 * 64];
  __shared__ unsigned short Bs[128 * 64];
  const int m0 = blockIdx.y * 128, n0 = blockIdx.x * 128;
  const int tid = threadIdx.x, w = tid >> 6, lane = tid & 63;
  const int l15 = lane & 15, l4 = lane >> 4;
  const int wr = w >> 1, wc = w & 1;
  const int srow = lane >> 3;
  const int schunk = (lane & 7) ^ (lane >> 3);   // inverse swizzle on global source

  f32x4 acc[4][4] = {};

  for (int k0 = 0; k0 < 1024; k0 += 64) {
    __syncthreads();
#pragma unroll
    for (int c = 0; c < 4; ++c) {
      const int rb = w * 32 + c * 8;
      const unsigned short* ga = A + (size_t)(m0 + rb + srow) * 1024 + k0 + schunk * 8;
      __builtin_amdgcn_global_load_lds(
          (const __attribute__((address_space(1))) void*)ga,
          (__attribute__((address_space(3))) void*)(&As[rb * 64]), 16, 0, 0);
      const unsigned short* gb = B + (size_t)(n0 + rb + srow) * 1024 + k0 + schunk * 8;
      __builtin_amdgcn_global_load_lds(
          (const __attribute__((address_space(1))) void*)gb,
          (__attribute__((address_space(3))) void*)(&Bs[rb * 64]), 16, 0, 0);
    }
    __syncthreads();
#pragma unroll
    for (int kk = 0; kk < 2; ++kk) {
      bf16x8 af[4], bfr[4];
#pragma unroll
      for (int m = 0; m < 4; m++) {
        const int row = wr * 64 + m * 16 + l15;
        af[m] = *(const bf16x8*)(&As[row * 64 + (((kk * 4 + l4) ^ (l15 & 7)) * 8)]);
      }
#pragma unroll
      for (int n = 0; n < 4; n++) {
        const int row = wc * 64 + n * 16 + l15;
        bfr[n] = *(const bf16x8*)(&Bs[row * 64 + (((kk * 4 + l4) ^ (l15 & 7)) * 8)]);
      }
#pragma unroll
      for (int m = 0; m < 4; m++)
#pragma unroll
        for (int n = 0; n < 4; n++)
          acc[m][n] = MFMA16(af[m], bfr[n], acc[m][n]);
    }
  }

  const bool rope = (n0 < 2048);
  unsigned short* dst = (n0 < 1024) ? Qb : (n0 < 2048 ? Kb : Vb);
  const int cbase = (n0 & 1023);
#pragma unroll
  for (int m = 0; m < 4; m++) {
#pragma unroll
    for (int n = 0; n < 4; n++) {
#pragma unroll
      for (int r = 0; r < 4; r++) {
        int row = m0 + wr * 64 + m * 16 + l4 * 4 + r;
        int col = cbase + wc * 64 + n * 16 + l15;
        float v = acc[m][n][r];
        float pv = __shfl_xor(v, 1, 64);      // value of col^1 (lives in lane^1)
        unsigned pk;
        if (rope) {
          float x1 = (l15 & 1) ? pv : v;
          float x2 = (l15 & 1) ? v : pv;
          int pos = row & 2047;
          int pi = (col & 63) >> 1;
          float c = cosT[pos * 32 + pi], s = sinT[pos * 32 + pi];
          float r1 = fmaf(x1, c, -x2 * s);
          float r2 = fmaf(x2, c, x1 * s);
          pk = (unsigned)f2b(r1) | ((unsigned)f2b(r2) << 16);
        } else {
          pk = (unsigned)f2b(v) | ((unsigned)f2b(pv) << 16);
        }
        if (!(l15 & 1))
          *(unsigned*)(dst + (size_t)row * 1024 + col) = pk;
      }
    }
  }
}

// ---------------- GEMM 2: output projection (BK=64, XOR-swizzled LDS) ----------------

__global__ __launch_bounds__(256) void gemm_out_kernel(
    const unsigned short* __restrict__ A,    // Ob [4096][1024]
    const unsigned short* __restrict__ B,    // Wob [1024][1024]
    float* __restrict__ out) {
  __shared__ unsigned short As[128 * 64];
  __shared__ unsigned short Bs[128 * 64];
  const int m0 = blockIdx.y * 128, n0 = blockIdx.x * 128;
  const int tid = threadIdx.x, w = tid >> 6, lane = tid & 63;
  const int l15 = lane & 15, l4 = lane >> 4;
  const int wr = w >> 1, wc = w & 1;
  const int srow = lane >> 3;
  const int schunk = (lane & 7) ^ (lane >> 3);

  f32x4 acc[4][4] = {};

  for (int k0 = 0; k0 < 1024; k0 += 64) {
    __syncthreads();
#pragma unroll
    for (int c = 0; c < 4; ++c) {
      const int rb = w * 32 + c * 8;
      const unsigned short* ga = A + (size_t)(m0 + rb + srow) * 1024 + k0 + schunk * 8;
      __builtin_amdgcn_global_load_lds(
          (const __attribute__((address_space(1))) void*)ga,
          (__attribute__((address_space(3))) void*)(&As[rb * 64]), 16, 0, 0);
      const unsigned short* gb = B + (size_t)(n0 + rb + srow) * 1024 + k0 + schunk * 8;
      __builtin_amdgcn_global_load_lds(
          (const __attribute__((address_space(1))) void*)gb,
          (__attribute__((address_space(3))) void*)(&Bs[rb * 64]), 16, 0, 0);
    }
    __syncthreads();
#pragma unroll
    for (int kk = 0; kk < 2; ++kk) {
      bf16x8 af[4], bfr[4];
#pragma unroll
      for (int m = 0; m < 4; m++) {
        const int row = wr * 64 + m * 16 + l15;
        af[m] = *(const bf16x8*)(&As[row * 64 + (((kk * 4 + l4) ^ (l15 & 7)) * 8)]);
      }
#pragma unroll
      for (int n = 0; n < 4; n++) {
        const int row = wc * 64 + n * 16 + l15;
        bfr[n] = *(const bf16x8*)(&Bs[row * 64 + (((kk * 4 + l4) ^ (l15 & 7)) * 8)]);
      }
#pragma unroll
      for (int m = 0; m < 4; m++)
#pragma unroll
        for (int n = 0; n < 4; n++)
          acc[m][n] = MFMA16(af[m], bfr[n], acc[m][n]);
    }
  }

#pragma unroll
  for (int m = 0; m < 4; m++)
#pragma unroll
    for (int n = 0; n < 4; n++)
#pragma unroll
      for (int r = 0; r < 4; r++) {
        int row = m0 + wr * 64 + m * 16 + l4 * 4 + r;
        int col = n0 + wc * 64 + n * 16 + l15;
        out[(size_t)row * 1024 + col] = acc[m][n][r];
      }
}

// ---------------- V transpose: Vb[4096][1024] -> VbT[32 bh][64 dk][2048 seq] ----------------

__global__ __launch_bounds__(256) void transpose_v(
    const unsigned short* __restrict__ Vb, unsigned short* __restrict__ VbT) {
  __shared__ unsigned short T[128][72];
  const int bh = blockIdx.x, st = blockIdx.y;   // 32 x 16 (128 seq per tile)
  const int b = bh >> 4, h = bh & 15;
  const int tid = threadIdx.x;
  {
    const int r = tid >> 1, c = (tid & 1) * 32;
    const unsigned short* g = Vb + (size_t)(b * 2048 + st * 128 + r) * 1024 + h * 64 + c;
#pragma unroll
    for (int j = 0; j < 4; ++j)
      *(int4v*)(&T[r][c + j * 8]) = *(const int4v*)(g + j * 8);
  }
  __syncthreads();
  {
    const int dk = tid & 63, sc = (tid >> 6) * 32;
    unsigned pk[16];
#pragma unroll
    for (int j = 0; j < 16; ++j)
      pk[j] = (unsigned)T[sc + 2 * j][dk] | ((unsigned)T[sc + 2 * j + 1][dk] << 16);
    unsigned short* g = VbT + (size_t)bh * 131072 + (size_t)dk * 2048 + st * 128 + sc;
#pragma unroll
    for (int j = 0; j < 4; ++j) {
      int4v ov;
      ov[0] = (int)pk[j * 4 + 0]; ov[1] = (int)pk[j * 4 + 1];
      ov[2] = (int)pk[j * 4 + 2]; ov[3] = (int)pk[j * 4 + 3];
      *(int4v*)(g + j * 8) = ov;
    }
  }
}

// ---------------- Flash attention: paired q-chunks, 3-buf counted-vmcnt pipeline --------

__device__ __forceinline__ void stage_tiles(const unsigned short* __restrict__ Kgb,
                                            const unsigned short* __restrict__ Vgb,
                                            unsigned short* KsBuf, unsigned short* VsBuf,
                                            int kv0, int w, int lane) {
#pragma unroll
  for (int c = 0; c < 2; ++c) {
    const int rowbase = w * 16 + c * 8;
    const int row = rowbase + (lane >> 3);
    const int chunk = (lane & 7) ^ (lane >> 3);    // inverse swizzle on global source
    const unsigned short* gk = Kgb + (size_t)(kv0 + row) * 1024 + chunk * 8;
    __builtin_amdgcn_global_load_lds(
        (const __attribute__((address_space(1))) void*)gk,
        (__attribute__((address_space(3))) void*)(KsBuf + rowbase * 64), 16, 0, 0);
    const unsigned short* gv = Vgb + (size_t)row * 2048 + kv0 + chunk * 8;
    __builtin_amdgcn_global_load_lds(
        (const __attribute__((address_space(1))) void*)gv,
        (__attribute__((address_space(3))) void*)(VsBuf + rowbase * 64), 16, 0, 0);
  }
}

__device__ __forceinline__ void attn_chunk(
    int qt, int b, int h, int w, int lane,
    const unsigned short* __restrict__ Qb,
    const unsigned short* __restrict__ Kgb,
    const unsigned short* __restrict__ Vgb,
    unsigned short* __restrict__ Ob,
    unsigned short (*Ks)[64 * 64], unsigned short (*Vs)[64 * 64]) {
  const int l31 = lane & 31, l32 = lane >> 5;
  const int sw = l31 & 7;

  const unsigned short* qptr =
      Qb + (size_t)(b * 2048 + qt * 128 + w * 32 + l31) * 1024 + h * 64 + l32 * 8;
  bf16x8 qa[4];
#pragma unroll
  for (int kk = 0; kk < 4; ++kk) qa[kk] = *(const bf16x8*)(qptr + kk * 16);

  f32x16 oacc[2] = {};
  float m = -3e38f, l = 0.f;

  const int nt = 2 * qt + 2;
  // prologue: 2 tiles in flight
  stage_tiles(Kgb, Vgb, Ks[0], Vs[0], 0, w, lane);
  if (nt > 1) stage_tiles(Kgb, Vgb, Ks[1], Vs[1], 64, w, lane);

  int ib = 0, is_ = 2;
  for (int t = 0; t < nt; ++t) {
    if (t < nt - 1) {
      asm volatile("s_waitcnt vmcnt(4)" ::: "memory");
    } else {
      asm volatile("s_waitcnt vmcnt(0)" ::: "memory");
    }
    __builtin_amdgcn_s_barrier();
    __builtin_amdgcn_sched_barrier(0);
    if (t + 2 < nt)
      stage_tiles(Kgb, Vgb, Ks[is_], Vs[is_], (t + 2) * 64, w, lane);

    // QK^T swapped: St = mfma32(K_frag, Q_frag) -> S^T[kv][q], q = l31
    const char* ksb = (const char*)Ks[ib];
    f32x16 st[2];
#pragma unroll
    for (int f = 0; f < 2; ++f) {
      const char* kb = ksb + (f * 32 + l31) * 128;
      f32x16 z = {};
#pragma unroll
      for (int kk = 0; kk < 4; ++kk) {
        bf16x8 kf = *(const bf16x8*)(kb + ((((kk << 1) | l32) ^ sw) * 16));
        z = MFMA32(kf, qa[kk], z);
      }
      st[f] = z;
    }

    // causal mask (diagonal tiles only)
    if (t >= 2 * qt + (w >> 1)) {
      const int qg = qt * 128 + w * 32 + l31;
      const int kvb = t * 64 + 4 * l32;
#pragma unroll
      for (int f = 0; f < 2; ++f)
#pragma unroll
        for (int reg = 0; reg < 16; ++reg) {
          int kv = kvb + 32 * f + (reg & 3) + 8 * (reg >> 2);
          if (kv > qg) st[f][reg] = -3e38f;
        }
    }

    // row max: in-register tree + 1 swap across lane halves
    float a8[8];
#pragma unroll
    for (int j = 0; j < 8; ++j)
      a8[j] = fmaxf(fmaxf(st[0][j], st[0][j + 8]), fmaxf(st[1][j], st[1][j + 8]));
    float pm = fmaxf(fmaxf(fmaxf(a8[0], a8[1]), fmaxf(a8[2], a8[3])),
                     fmaxf(fmaxf(a8[4], a8[5]), fmaxf(a8[6], a8[7])));
    pm = fmaxf(pm, __shfl_xor(pm, 32, 64));

    // defer-max: rescale only when running max grew by > 8 (log2 domain)
    if (!__all(pm - m <= 8.0f)) {
      float mn = fmaxf(m, pm);
      float al = fexp2(m - mn);
      l *= al;
#pragma unroll
      for (int df = 0; df < 2; ++df)
#pragma unroll
        for (int reg = 0; reg < 16; ++reg) oacc[df][reg] *= al;
      m = mn;
    }

    // p = exp2(s - m), pack to bf16 pairs
    unsigned pku[2][4][2];
    float rs0 = 0.f, rs1 = 0.f;
#pragma unroll
    for (int f = 0; f < 2; ++f)
#pragma unroll
      for (int rr = 0; rr < 4; ++rr)
#pragma unroll
        for (int i = 0; i < 2; ++i) {
          float p0 = fexp2(st[f][4 * rr + 2 * i] - m);
          float p1 = fexp2(st[f][4 * rr + 2 * i + 1] - m);
          rs0 += p0; rs1 += p1;
          pku[f][rr][i] = cvtpk(p0, p1);
        }
    float rs = rs0 + rs1;
    rs += __shfl_xor(rs, 32, 64);
    l += rs;

    // redistribute P^T into B-operand frags via permlane32_swap
    union FB { unsigned u[4]; bf16x8 v; };
    FB pfrag[4];
#pragma unroll
    for (int kk = 0; kk < 4; ++kk) {
      const int f = kk >> 1, kl = kk & 1;
      unsigned o00, o10, o01, o11;
      plswap(pku[f][2 * kl][0], pku[f][2 * kl + 1][0], o00, o10);
      plswap(pku[f][2 * kl][1], pku[f][2 * kl + 1][1], o01, o11);
      pfrag[kk].u[0] = o00; pfrag[kk].u[1] = o01;
      pfrag[kk].u[2] = o10; pfrag[kk].u[3] = o11;
    }

    // PV swapped: O^T[d][q] += mfma32(V^T_frag, P^T_frag)
    const char* vsb = (const char*)Vs[ib];
#pragma unroll
    for (int df = 0; df < 2; ++df) {
      const char* vb = vsb + (df * 32 + l31) * 128;
#pragma unroll
      for (int kk = 0; kk < 4; ++kk) {
        bf16x8 vf = *(const bf16x8*)(vb + ((((kk << 1) | l32) ^ sw) * 16));
        oacc[df] = MFMA32(vf, pfrag[kk].v, oacc[df]);
      }
    }

    ib = (ib == 2) ? 0 : ib + 1;
    is_ = (is_ == 2) ? 0 : is_ + 1;
  }

  // epilogue: O[q][d], d = df*32 + 8*rr + 4*l32 + 2i (+1)
  const float inv = 1.0f / l;
  unsigned short* ob =
      Ob + (size_t)(b * 2048 + qt * 128 + w * 32 + l31) * 1024 + h * 64 + 4 * l32;
#pragma unroll
  for (int df = 0; df < 2; ++df)
#pragma unroll
    for (int rr = 0; rr < 4; ++rr)
#pragma unroll
      for (int i = 0; i < 2; ++i) {
        unsigned pk2 = (unsigned)f2b(oacc[df][4 * rr + 2 * i] * inv) |
                       ((unsigned)f2b(oacc[df][4 * rr + 2 * i + 1] * inv) << 16);
        *(unsigned*)(ob + df * 32 + rr * 8 + 2 * i) = pk2;
      }
}

__global__ __launch_bounds__(256) void attn_kernel(
    const unsigned short* __restrict__ Qb,
    const unsigned short* __restrict__ Kb,
    const unsigned short* __restrict__ VbT,   // [32][64][2048]
    unsigned short* __restrict__ Ob) {
  __shared__ unsigned short Ks[3][64 * 64];   // 3-deep pipeline, chunk-swizzled
  __shared__ unsigned short Vs[3][64 * 64];
  const int bh = blockIdx.x;                  // fastest -> same bh lands on one XCD
  const int pair = blockIdx.y;                // 0..7
  const int b = bh >> 4, h = bh & 15;
  const int tid = threadIdx.x, w = tid >> 6, lane = tid & 63;

  const unsigned short* Kgb = Kb + (size_t)b * 2048 * 1024 + h * 64;
  const unsigned short* Vgb = VbT + (size_t)bh * 131072;

  attn_chunk(pair, b, h, w, lane, Qb, Kgb, Vgb, Ob, Ks, Vs);
  __syncthreads();   // all waves done reading chunk-A tiles before re-staging
  attn_chunk(15 - pair, b, h, w, lane, Qb, Kgb, Vgb, Ob, Ks, Vs);
}

// ---------------- launch ----------------

extern "C" void kernel_launch(void* const* d_in, const int* in_sizes, int n_in,
                              void* d_out, int out_size, void* d_ws, size_t ws_size,
                              hipStream_t stream) {
  (void)in_sizes; (void)n_in; (void)out_size; (void)ws_size;
  const float* x  = (const float*)d_in[0];
  const int*  tp  = (const int*)d_in[1];
  const float* Wq = (const float*)d_in[2];
  const float* Wk = (const float*)d_in[3];
  const float* Wv = (const float*)d_in[4];
  const float* Wo = (const float*)d_in[5];
  float* out = (float*)d_out;

  char* ws = (char*)d_ws;
  unsigned short* xb    = (unsigned short*)(ws);                       // 8MB
  unsigned short* VbT   = (unsigned short*)(ws);                       // reuses xb
  unsigned short* Wqkvb = (unsigned short*)(ws + (8ull << 20));        // 6MB
  unsigned short* Wob   = (unsigned short*)(ws + (14ull << 20));       // 2MB
  unsigned short* Qb    = (unsigned short*)(ws + (16ull << 20));       // 8MB
  unsigned short* Kb    = (unsigned short*)(ws + (24ull << 20));       // 8MB
  unsigned short* Vb    = (unsigned short*)(ws + (32ull << 20));       // 8MB
  unsigned short* Ob    = (unsigned short*)(ws + (32ull << 20));       // reuses Vb
  float* cosT = (float*)(ws + (40ull << 20));
  float* sinT = (float*)(ws + (40ull << 20) + 2048 * 32 * 4);

  prep_kernel<<<8256, 256, 0, stream>>>(x, Wq, Wk, Wv, Wo, tp, xb, Wqkvb, Wob, cosT, sinT);
  gemm_qkv_kernel<<<dim3(24, 32), 256, 0, stream>>>(xb, Wqkvb, Qb, Kb, Vb, cosT, sinT);
  transpose_v<<<dim3(32, 16), 256, 0, stream>>>(Vb, VbT);
  attn_kernel<<<dim3(32, 8), 256, 0, stream>>>(Qb, Kb, VbT, Ob);
  gemm_out_kernel<<<dim3(8, 32), 256, 0, stream>>>(Ob, Wob, out);
}

// Round 6
// 119.168 us; speedup vs baseline: 1.3808x; 1.3178x over previous
//
#include <hip/hip_runtime.h>
#include <hip/hip_bf16.h>

// MHA forward: b=2, s=2048, d=1024, h=16, dk=64. fp32 in/out, bf16 MFMA internally.
// ws layout (40.5 MB):
//   0      : xb [4096][1024] bf16 (8MB)  -- dead after gemm_qkv, reused as Ob (attn out)
//   8 MB   : Wqkvb [3072][1024] bf16 (6MB)  rows 0-1023=Wq*log2e/8, 1024-2047=Wk, 2048-3071=Wv
//   14 MB  : Wob [1024][1024] bf16 (2MB)
//   16 MB  : Qb [4096][1024] bf16 (8MB)  (RoPE'd, log2-domain scale)
//   24 MB  : Kb [4096][1024] bf16 (8MB)  (RoPE'd)
//   32 MB  : VbT [32 bh][64 dk][2048 seq] bf16 (8MB)  (written transposed by gemm_qkv)
//   40 MB  : cosT [2048][32] f32, sinT [2048][32] f32

typedef __attribute__((ext_vector_type(8))) __bf16 bf16x8;
typedef __attribute__((ext_vector_type(4))) float f32x4;
typedef __attribute__((ext_vector_type(16))) float f32x16;
typedef __attribute__((ext_vector_type(4))) int int4v;
typedef __attribute__((ext_vector_type(2))) unsigned int uint2v;

#define MFMA16(a, b, c) __builtin_amdgcn_mfma_f32_16x16x32_bf16(a, b, c, 0, 0, 0)
#define MFMA32(a, b, c) __builtin_amdgcn_mfma_f32_32x32x16_bf16(a, b, c, 0, 0, 0)

__device__ inline unsigned short f2b(float f) {
  unsigned u = __builtin_bit_cast(unsigned, f);
  u = (u + 0x7FFF + ((u >> 16) & 1)) >> 16;   // RNE, finite inputs only
  return (unsigned short)u;
}

__device__ inline unsigned pk2b(float lo, float hi) {
  return (unsigned)f2b(lo) | ((unsigned)f2b(hi) << 16);
}

__device__ inline unsigned cvtpk(float lo, float hi) {
  unsigned r;
  asm("v_cvt_pk_bf16_f32 %0, %1, %2" : "=v"(r) : "v"(lo), "v"(hi));
  return r;
}

__device__ inline void plswap(unsigned a, unsigned b, unsigned& o0, unsigned& o1) {
#if __has_builtin(__builtin_amdgcn_permlane32_swap)
  auto r = __builtin_amdgcn_permlane32_swap(a, b, false, false);
  o0 = r[0];
  o1 = r[1];
#else
  unsigned sa = (unsigned)__shfl_xor((int)a, 32, 64);
  unsigned sb = (unsigned)__shfl_xor((int)b, 32, 64);
  bool hi = (threadIdx.x & 32) != 0;
  o0 = hi ? sb : a;
  o1 = hi ? b : sa;
#endif
}

__device__ inline float fexp2(float x) {
#if __has_builtin(__builtin_amdgcn_exp2f)
  return __builtin_amdgcn_exp2f(x);
#else
  return exp2f(x);
#endif
}

// ---------------- fused prep ----------------

__device__ inline void cvt4(const float* __restrict__ s, unsigned short* __restrict__ d,
                            int i, float sc) {
  float4 v = *(const float4*)(s + i);
  uint2v p = {pk2b(v.x * sc, v.y * sc), pk2b(v.z * sc, v.w * sc)};
  *(uint2v*)(d + i) = p;
}

__global__ __launch_bounds__(256) void prep_kernel(
    const float* __restrict__ x, const float* __restrict__ Wq,
    const float* __restrict__ Wk, const float* __restrict__ Wv,
    const float* __restrict__ Wo, const int* __restrict__ tp,
    unsigned short* __restrict__ xb, unsigned short* __restrict__ Wqkvb,
    unsigned short* __restrict__ Wob, float* __restrict__ cosT,
    float* __restrict__ sinT) {
  int t = blockIdx.x * 256 + threadIdx.x;
  if (t < 1048576) {
    cvt4(x, xb, t * 4, 1.0f);
  } else if (t < 1310720) {
    cvt4(Wq, Wqkvb, (t - 1048576) * 4, 0.18033688f);   // (1/8)*log2(e)
  } else if (t < 1572864) {
    cvt4(Wk, Wqkvb + 1048576, (t - 1310720) * 4, 1.0f);
  } else if (t < 1835008) {
    cvt4(Wv, Wqkvb + 2097152, (t - 1572864) * 4, 1.0f);
  } else if (t < 2097152) {
    cvt4(Wo, Wob, (t - 1835008) * 4, 1.0f);
  } else {
    int base = (t - 2097152) * 4;
#pragma unroll
    for (int j = 0; j < 4; ++j) {
      int idx = base + j;
      int p = idx >> 5, i = idx & 31;
      float pos = (float)tp[p];
      float freq = powf(10000.0f, -(float)i / 32.0f);
      float ang = pos * freq;
      cosT[idx] = cosf(ang);
      sinT[idx] = sinf(ang);
    }
  }
}

// ---------------- GEMM staging (BK=64, xor-swizzled, B rows bit-permuted) ----------------
// B-row permutation: LDS row r holds global weight row (r&96)|((r&15)<<1)|((r>>4)&1).
// => wave frag-pair (2k,2k+1) at lane l15 holds output-column pair (c, c+1), c = wc*64+32k+2*l15.
// RoPE partners are in-lane; stores pack to u32; no shfl, no idle lanes.

__device__ __forceinline__ void g_stage(const unsigned short* __restrict__ A,
                                        const unsigned short* __restrict__ B,
                                        unsigned short* __restrict__ As,
                                        unsigned short* __restrict__ Bs,
                                        int m0, int n0, int k0, int w, int lane) {
  const int srow = lane >> 3;
  const int schunk = (lane & 7) ^ srow;          // inverse swizzle on global source
#pragma unroll
  for (int c = 0; c < 4; ++c) {
    const int rb = w * 32 + c * 8;
    const unsigned short* ga = A + (size_t)(m0 + rb + srow) * 1024 + k0 + schunk * 8;
    __builtin_amdgcn_global_load_lds(
        (const __attribute__((address_space(1))) void*)ga,
        (__attribute__((address_space(3))) void*)(As + rb * 64), 16, 0, 0);
    const int rl = rb + srow;
    const int rB = n0 + (rl & 96) + ((rl & 15) << 1) + ((rl >> 4) & 1);
    const unsigned short* gb = B + (size_t)rB * 1024 + k0 + schunk * 8;
    __builtin_amdgcn_global_load_lds(
        (const __attribute__((address_space(1))) void*)gb,
        (__attribute__((address_space(3))) void*)(Bs + rb * 64), 16, 0, 0);
  }
}

// ---------------- GEMM 1: QKV projection + RoPE epilogue, 2-phase pipeline ----------------

__global__ __launch_bounds__(256) void gemm_qkv_kernel(
    const unsigned short* __restrict__ A,    // xb
    const unsigned short* __restrict__ B,    // Wqkvb
    unsigned short* __restrict__ Qb, unsigned short* __restrict__ Kb,
    unsigned short* __restrict__ VbT,        // [32][64][2048]
    const float* __restrict__ cosT, const float* __restrict__ sinT) {
  __shared__ unsigned short As[2][128 * 64];
  __shared__ unsigned short Bs[2][128 * 64];
  // XCD swizzle: 768 blocks, 96 per XCD
  const int bid = blockIdx.x;
  const int sw = (bid & 7) * 96 + (bid >> 3);
  const int n0 = (sw % 24) * 128, m0 = (sw / 24) * 128;
  const int tid = threadIdx.x, w = tid >> 6, lane = tid & 63;
  const int l15 = lane & 15, l4 = lane >> 4;
  const int wr = w >> 1, wc = w & 1;

  f32x4 acc[4][4] = {};

  g_stage(A, B, As[0], Bs[0], m0, n0, 0, w, lane);
  asm volatile("s_waitcnt vmcnt(0)" ::: "memory");
  __builtin_amdgcn_s_barrier();

  int cur = 0;
  for (int k0 = 0; k0 < 1024; k0 += 64) {
    if (k0 + 64 < 1024)
      g_stage(A, B, As[cur ^ 1], Bs[cur ^ 1], m0, n0, k0 + 64, w, lane);
#pragma unroll
    for (int kk = 0; kk < 2; ++kk) {
      bf16x8 af[4], bfr[4];
#pragma unroll
      for (int m = 0; m < 4; m++) {
        const int row = wr * 64 + m * 16 + l15;
        af[m] = *(const bf16x8*)(&As[cur][row * 64 + (((kk * 4 + l4) ^ (l15 & 7)) * 8)]);
      }
#pragma unroll
      for (int n = 0; n < 4; n++) {
        const int row = wc * 64 + n * 16 + l15;
        bfr[n] = *(const bf16x8*)(&Bs[cur][row * 64 + (((kk * 4 + l4) ^ (l15 & 7)) * 8)]);
      }
#pragma unroll
      for (int m = 0; m < 4; m++)
#pragma unroll
        for (int n = 0; n < 4; n++)
          acc[m][n] = MFMA16(af[m], bfr[n], acc[m][n]);
    }
    asm volatile("s_waitcnt vmcnt(0)" ::: "memory");
    __builtin_amdgcn_s_barrier();
    cur ^= 1;
  }

  const int cbase = n0 & 1023;
  if (n0 < 2048) {
    // Q or K: RoPE in-lane (pairs are frag 2k / 2k+1), packed u32 stores
    unsigned short* dst = (n0 < 1024) ? Qb : Kb;
#pragma unroll
    for (int m = 0; m < 4; m++) {
      const int row0 = m0 + wr * 64 + m * 16 + l4 * 4;
#pragma unroll
      for (int k = 0; k < 2; k++) {
        const int col = cbase + wc * 64 + k * 32 + 2 * l15;
        const int pi = k * 16 + l15;
#pragma unroll
        for (int r = 0; r < 4; r++) {
          const int pos = (row0 + r) & 2047;
          float c = cosT[pos * 32 + pi], s = sinT[pos * 32 + pi];
          float v0 = acc[m][2 * k][r], v1 = acc[m][2 * k + 1][r];
          float r1 = fmaf(v0, c, -v1 * s);
          float r2 = fmaf(v1, c, v0 * s);
          *(unsigned*)(dst + (size_t)(row0 + r) * 1024 + col) = pk2b(r1, r2);
        }
      }
    }
  } else {
    // V: store directly transposed into VbT[bh][dk][seq] (4 consecutive seq per lane)
#pragma unroll
    for (int m = 0; m < 4; m++) {
      const int row0 = m0 + wr * 64 + m * 16 + l4 * 4;
      const int bb = row0 >> 11, seq = row0 & 2047;
#pragma unroll
      for (int k = 0; k < 2; k++) {
        const int dkg = cbase + wc * 64 + k * 32 + 2 * l15;
        const int h = dkg >> 6, dk = dkg & 63;
        unsigned short* vp = VbT + (size_t)(bb * 16 + h) * 131072 + dk * 2048 + seq;
        uint2v e = {pk2b(acc[m][2 * k][0], acc[m][2 * k][1]),
                    pk2b(acc[m][2 * k][2], acc[m][2 * k][3])};
        *(uint2v*)vp = e;
        uint2v o = {pk2b(acc[m][2 * k + 1][0], acc[m][2 * k + 1][1]),
                    pk2b(acc[m][2 * k + 1][2], acc[m][2 * k + 1][3])};
        *(uint2v*)(vp + 2048) = o;
      }
    }
  }
}

// ---------------- GEMM 2: output projection, 2-phase pipeline ----------------

__global__ __launch_bounds__(256) void gemm_out_kernel(
    const unsigned short* __restrict__ A,    // Ob [4096][1024]
    const unsigned short* __restrict__ B,    // Wob [1024][1024]
    float* __restrict__ out) {
  __shared__ unsigned short As[2][128 * 64];
  __shared__ unsigned short Bs[2][128 * 64];
  // XCD swizzle: 256 blocks, 32 per XCD
  const int bid = blockIdx.x;
  const int sw = (bid & 7) * 32 + (bid >> 3);
  const int n0 = (sw % 8) * 128, m0 = (sw / 8) * 128;
  const int tid = threadIdx.x, w = tid >> 6, lane = tid & 63;
  const int l15 = lane & 15, l4 = lane >> 4;
  const int wr = w >> 1, wc = w & 1;

  f32x4 acc[4][4] = {};

  g_stage(A, B, As[0], Bs[0], m0, n0, 0, w, lane);
  asm volatile("s_waitcnt vmcnt(0)" ::: "memory");
  __builtin_amdgcn_s_barrier();

  int cur = 0;
  for (int k0 = 0; k0 < 1024; k0 += 64) {
    if (k0 + 64 < 1024)
      g_stage(A, B, As[cur ^ 1], Bs[cur ^ 1], m0, n0, k0 + 64, w, lane);
#pragma unroll
    for (int kk = 0; kk < 2; ++kk) {
      bf16x8 af[4], bfr[4];
#pragma unroll
      for (int m = 0; m < 4; m++) {
        const int row = wr * 64 + m * 16 + l15;
        af[m] = *(const bf16x8*)(&As[cur][row * 64 + (((kk * 4 + l4) ^ (l15 & 7)) * 8)]);
      }
#pragma unroll
      for (int n = 0; n < 4; n++) {
        const int row = wc * 64 + n * 16 + l15;
        bfr[n] = *(const bf16x8*)(&Bs[cur][row * 64 + (((kk * 4 + l4) ^ (l15 & 7)) * 8)]);
      }
#pragma unroll
      for (int m = 0; m < 4; m++)
#pragma unroll
        for (int n = 0; n < 4; n++)
          acc[m][n] = MFMA16(af[m], bfr[n], acc[m][n]);
    }
    asm volatile("s_waitcnt vmcnt(0)" ::: "memory");
    __builtin_amdgcn_s_barrier();
    cur ^= 1;
  }

  // permuted-B epilogue: frag-pair (2k,2k+1) = cols (c, c+1); float2 stores
#pragma unroll
  for (int m = 0; m < 4; m++) {
    const int row0 = m0 + wr * 64 + m * 16 + l4 * 4;
#pragma unroll
    for (int k = 0; k < 2; k++) {
      const int col = n0 + wc * 64 + k * 32 + 2 * l15;
#pragma unroll
      for (int r = 0; r < 4; r++) {
        float2 v = {acc[m][2 * k][r], acc[m][2 * k + 1][r]};
        *(float2*)(out + (size_t)(row0 + r) * 1024 + col) = v;
      }
    }
  }
}

// ---------------- Flash attention: paired q-chunks, 3-buf counted-vmcnt pipeline --------

__device__ __forceinline__ void stage_tiles(const unsigned short* __restrict__ Kgb,
                                            const unsigned short* __restrict__ Vgb,
                                            unsigned short* KsBuf, unsigned short* VsBuf,
                                            int kv0, int w, int lane) {
#pragma unroll
  for (int c = 0; c < 2; ++c) {
    const int rowbase = w * 16 + c * 8;
    const int row = rowbase + (lane >> 3);
    const int chunk = (lane & 7) ^ (lane >> 3);    // inverse swizzle on global source
    const unsigned short* gk = Kgb + (size_t)(kv0 + row) * 1024 + chunk * 8;
    __builtin_amdgcn_global_load_lds(
        (const __attribute__((address_space(1))) void*)gk,
        (__attribute__((address_space(3))) void*)(KsBuf + rowbase * 64), 16, 0, 0);
    const unsigned short* gv = Vgb + (size_t)row * 2048 + kv0 + chunk * 8;
    __builtin_amdgcn_global_load_lds(
        (const __attribute__((address_space(1))) void*)gv,
        (__attribute__((address_space(3))) void*)(VsBuf + rowbase * 64), 16, 0, 0);
  }
}

__device__ __forceinline__ void attn_chunk(
    int qt, int b, int h, int w, int lane,
    const unsigned short* __restrict__ Qb,
    const unsigned short* __restrict__ Kgb,
    const unsigned short* __restrict__ Vgb,
    unsigned short* __restrict__ Ob,
    unsigned short (*Ks)[64 * 64], unsigned short (*Vs)[64 * 64]) {
  const int l31 = lane & 31, l32 = lane >> 5;
  const int sw = l31 & 7;

  const unsigned short* qptr =
      Qb + (size_t)(b * 2048 + qt * 128 + w * 32 + l31) * 1024 + h * 64 + l32 * 8;
  bf16x8 qa[4];
#pragma unroll
  for (int kk = 0; kk < 4; ++kk) qa[kk] = *(const bf16x8*)(qptr + kk * 16);

  f32x16 oacc[2] = {};
  float m = -3e38f, l = 0.f;

  const int nt = 2 * qt + 2;
  stage_tiles(Kgb, Vgb, Ks[0], Vs[0], 0, w, lane);
  if (nt > 1) stage_tiles(Kgb, Vgb, Ks[1], Vs[1], 64, w, lane);

  int ib = 0, is_ = 2;
  for (int t = 0; t < nt; ++t) {
    if (t < nt - 1) {
      asm volatile("s_waitcnt vmcnt(4)" ::: "memory");
    } else {
      asm volatile("s_waitcnt vmcnt(0)" ::: "memory");
    }
    __builtin_amdgcn_s_barrier();
    __builtin_amdgcn_sched_barrier(0);
    if (t + 2 < nt)
      stage_tiles(Kgb, Vgb, Ks[is_], Vs[is_], (t + 2) * 64, w, lane);

    // QK^T swapped: St = mfma32(K_frag, Q_frag) -> S^T[kv][q], q = l31
    const char* ksb = (const char*)Ks[ib];
    f32x16 st[2];
#pragma unroll
    for (int f = 0; f < 2; ++f) {
      const char* kb = ksb + (f * 32 + l31) * 128;
      f32x16 z = {};
#pragma unroll
      for (int kk = 0; kk < 4; ++kk) {
        bf16x8 kf = *(const bf16x8*)(kb + ((((kk << 1) | l32) ^ sw) * 16));
        z = MFMA32(kf, qa[kk], z);
      }
      st[f] = z;
    }

    // causal mask (diagonal tiles only)
    if (t >= 2 * qt + (w >> 1)) {
      const int qg = qt * 128 + w * 32 + l31;
      const int kvb = t * 64 + 4 * l32;
#pragma unroll
      for (int f = 0; f < 2; ++f)
#pragma unroll
        for (int reg = 0; reg < 16; ++reg) {
          int kv = kvb + 32 * f + (reg & 3) + 8 * (reg >> 2);
          if (kv > qg) st[f][reg] = -3e38f;
        }
    }

    // row max: in-register tree + 1 swap across lane halves
    float a8[8];
#pragma unroll
    for (int j = 0; j < 8; ++j)
      a8[j] = fmaxf(fmaxf(st[0][j], st[0][j + 8]), fmaxf(st[1][j], st[1][j + 8]));
    float pm = fmaxf(fmaxf(fmaxf(a8[0], a8[1]), fmaxf(a8[2], a8[3])),
                     fmaxf(fmaxf(a8[4], a8[5]), fmaxf(a8[6], a8[7])));
    pm = fmaxf(pm, __shfl_xor(pm, 32, 64));

    // defer-max: rescale only when running max grew by > 8 (log2 domain)
    if (!__all(pm - m <= 8.0f)) {
      float mn = fmaxf(m, pm);
      float al = fexp2(m - mn);
      l *= al;
#pragma unroll
      for (int df = 0; df < 2; ++df)
#pragma unroll
        for (int reg = 0; reg < 16; ++reg) oacc[df][reg] *= al;
      m = mn;
    }

    // p = exp2(s - m), pack to bf16 pairs
    unsigned pku[2][4][2];
    float rs0 = 0.f, rs1 = 0.f;
#pragma unroll
    for (int f = 0; f < 2; ++f)
#pragma unroll
      for (int rr = 0; rr < 4; ++rr)
#pragma unroll
        for (int i = 0; i < 2; ++i) {
          float p0 = fexp2(st[f][4 * rr + 2 * i] - m);
          float p1 = fexp2(st[f][4 * rr + 2 * i + 1] - m);
          rs0 += p0; rs1 += p1;
          pku[f][rr][i] = cvtpk(p0, p1);
        }
    float rs = rs0 + rs1;
    rs += __shfl_xor(rs, 32, 64);
    l += rs;

    // redistribute P^T into B-operand frags via permlane32_swap
    union FB { unsigned u[4]; bf16x8 v; };
    FB pfrag[4];
#pragma unroll
    for (int kk = 0; kk < 4; ++kk) {
      const int f = kk >> 1, kl = kk & 1;
      unsigned o00, o10, o01, o11;
      plswap(pku[f][2 * kl][0], pku[f][2 * kl + 1][0], o00, o10);
      plswap(pku[f][2 * kl][1], pku[f][2 * kl + 1][1], o01, o11);
      pfrag[kk].u[0] = o00; pfrag[kk].u[1] = o01;
      pfrag[kk].u[2] = o10; pfrag[kk].u[3] = o11;
    }

    // PV swapped: O^T[d][q] += mfma32(V^T_frag, P^T_frag)
    const char* vsb = (const char*)Vs[ib];
#pragma unroll
    for (int df = 0; df < 2; ++df) {
      const char* vb = vsb + (df * 32 + l31) * 128;
#pragma unroll
      for (int kk = 0; kk < 4; ++kk) {
        bf16x8 vf = *(const bf16x8*)(vb + ((((kk << 1) | l32) ^ sw) * 16));
        oacc[df] = MFMA32(vf, pfrag[kk].v, oacc[df]);
      }
    }

    ib = (ib == 2) ? 0 : ib + 1;
    is_ = (is_ == 2) ? 0 : is_ + 1;
  }

  // epilogue: O[q][d], d = df*32 + 8*rr + 4*l32 + 2i (+1)
  const float inv = 1.0f / l;
  unsigned short* ob =
      Ob + (size_t)(b * 2048 + qt * 128 + w * 32 + l31) * 1024 + h * 64 + 4 * l32;
#pragma unroll
  for (int df = 0; df < 2; ++df)
#pragma unroll
    for (int rr = 0; rr < 4; ++rr)
#pragma unroll
      for (int i = 0; i < 2; ++i) {
        *(unsigned*)(ob + df * 32 + rr * 8 + 2 * i) =
            pk2b(oacc[df][4 * rr + 2 * i] * inv, oacc[df][4 * rr + 2 * i + 1] * inv);
      }
}

__global__ __launch_bounds__(256) void attn_kernel(
    const unsigned short* __restrict__ Qb,
    const unsigned short* __restrict__ Kb,
    const unsigned short* __restrict__ VbT,   // [32][64][2048]
    unsigned short* __restrict__ Ob) {
  __shared__ unsigned short Ks[3][64 * 64];   // 3-deep pipeline, chunk-swizzled
  __shared__ unsigned short Vs[3][64 * 64];
  const int bh = blockIdx.x;                  // fastest -> same bh lands on one XCD
  const int pair = blockIdx.y;                // 0..7
  const int b = bh >> 4, h = bh & 15;
  const int tid = threadIdx.x, w = tid >> 6, lane = tid & 63;

  const unsigned short* Kgb = Kb + (size_t)b * 2048 * 1024 + h * 64;
  const unsigned short* Vgb = VbT + (size_t)bh * 131072;

  attn_chunk(pair, b, h, w, lane, Qb, Kgb, Vgb, Ob, Ks, Vs);
  __syncthreads();   // all waves done reading chunk-A tiles before re-staging
  attn_chunk(15 - pair, b, h, w, lane, Qb, Kgb, Vgb, Ob, Ks, Vs);
}

// ---------------- launch ----------------

extern "C" void kernel_launch(void* const* d_in, const int* in_sizes, int n_in,
                              void* d_out, int out_size, void* d_ws, size_t ws_size,
                              hipStream_t stream) {
  (void)in_sizes; (void)n_in; (void)out_size; (void)ws_size;
  const float* x  = (const float*)d_in[0];
  const int*  tp  = (const int*)d_in[1];
  const float* Wq = (const float*)d_in[2];
  const float* Wk = (const float*)d_in[3];
  const float* Wv = (const float*)d_in[4];
  const float* Wo = (const float*)d_in[5];
  float* out = (float*)d_out;

  char* ws = (char*)d_ws;
  unsigned short* xb    = (unsigned short*)(ws);                       // 8MB
  unsigned short* Ob    = (unsigned short*)(ws);                       // reuses xb
  unsigned short* Wqkvb = (unsigned short*)(ws + (8ull << 20));        // 6MB
  unsigned short* Wob   = (unsigned short*)(ws + (14ull << 20));       // 2MB
  unsigned short* Qb    = (unsigned short*)(ws + (16ull << 20));       // 8MB
  unsigned short* Kb    = (unsigned short*)(ws + (24ull << 20));       // 8MB
  unsigned short* VbT   = (unsigned short*)(ws + (32ull << 20));       // 8MB
  float* cosT = (float*)(ws + (40ull << 20));
  float* sinT = (float*)(ws + (40ull << 20) + 2048 * 32 * 4);

  prep_kernel<<<8256, 256, 0, stream>>>(x, Wq, Wk, Wv, Wo, tp, xb, Wqkvb, Wob, cosT, sinT);
  gemm_qkv_kernel<<<768, 256, 0, stream>>>(xb, Wqkvb, Qb, Kb, VbT, cosT, sinT);
  attn_kernel<<<dim3(32, 8), 256, 0, stream>>>(Qb, Kb, VbT, Ob);
  gemm_out_kernel<<<256, 256, 0, stream>>>(Ob, Wob, out);
}